// Round 1
// baseline (205.689 us; speedup 1.0000x reference)
//
#include <hip/hip_runtime.h>

typedef float f4 __attribute__((ext_vector_type(4)));

constexpr int B = 2, C = 16, D = 24, H = 48, W = 48;
constexpr int K = 27;
constexpr int SP = D * H * W;   // 55296 == P (stride 1, pad 1, dil 1, k=3)
constexpr int HW = H * W;

// x [B, C, S] -> xt [B, S, C]  (so one spatial point's 16 channels = one 64B block)
__global__ __launch_bounds__(256) void xpose_kernel(const float* __restrict__ x,
                                                    float* __restrict__ xt) {
    int t = blockIdx.x * blockDim.x + threadIdx.x;
    if (t >= B * SP) return;
    int s = t % SP, b = t / SP;
    const float* src = x + (size_t)b * C * SP + s;
    f4 v[4];
#pragma unroll
    for (int q = 0; q < 4; ++q)
#pragma unroll
        for (int j = 0; j < 4; ++j)
            v[q][j] = src[(size_t)(q * 4 + j) * SP];
    f4* dst = reinterpret_cast<f4*>(xt + (size_t)t * 16);
#pragma unroll
    for (int q = 0; q < 4; ++q) dst[q] = v[q];
}

template <bool XT>
__global__ __launch_bounds__(256) void deform_kernel(const float* __restrict__ xsrc,
                                                     const float* __restrict__ off,
                                                     float* __restrict__ out) {
    int tid = blockIdx.x * blockDim.x + threadIdx.x;
    if (tid >= B * K * SP) return;
    int p = tid % SP;
    int bk = tid / SP;
    int k = bk % K, b = bk / K;

    // offset channel layout: [B, K*3, P], channel = 3*k + {0,1,2}
    const float* ob = off + ((size_t)b * (3 * K) + 3 * k) * SP + p;
    float offd = ob[0];
    float offh = ob[(size_t)SP];
    float offw = ob[(size_t)2 * SP];

    int od = p / HW, rem = p - od * HW;
    int oh = rem / W, ow = rem - oh * W;
    int ki = k / 9, kr = k - ki * 9;
    int kj = kr / 3, kk = kr - kj * 3;

    float pd = (float)(od + ki - 1) + offd;
    float ph = (float)(oh + kj - 1) + offh;
    float pw = (float)(ow + kk - 1) + offw;

    float d0f = floorf(pd), h0f = floorf(ph), w0f = floorf(pw);
    float fd = pd - d0f, fh = ph - h0f, fw = pw - w0f;
    int d0 = (int)d0f, h0 = (int)h0f, w0 = (int)w0f;

    f4 acc[4] = {};

#pragma unroll
    for (int ci = 0; ci < 2; ++ci) {
        int ds = d0 + ci;
        bool vd = (ds >= 0) & (ds < D);
        float wd = ci ? fd : 1.0f - fd;
        int dc = min(max(ds, 0), D - 1);
#pragma unroll
        for (int cj = 0; cj < 2; ++cj) {
            int hs = h0 + cj;
            bool vh = (hs >= 0) & (hs < H);
            float wh = cj ? fh : 1.0f - fh;
            int hc = min(max(hs, 0), H - 1);
#pragma unroll
            for (int ck = 0; ck < 2; ++ck) {
                int ws = w0 + ck;
                bool vw = (ws >= 0) & (ws < W);
                float ww = ck ? fw : 1.0f - fw;
                int wc = min(max(ws, 0), W - 1);
                float wgt = (vd & vh & vw) ? wd * wh * ww : 0.0f;
                int idx = (dc * H + hc) * W + wc;
                if (XT) {
                    const f4* src =
                        reinterpret_cast<const f4*>(xsrc) + ((size_t)b * SP + idx) * 4;
#pragma unroll
                    for (int q = 0; q < 4; ++q) acc[q] += wgt * src[q];
                } else {
                    const float* src = xsrc + (size_t)b * C * SP + idx;
#pragma unroll
                    for (int c = 0; c < C; ++c)
                        acc[c >> 2][c & 3] += wgt * src[(size_t)c * SP];
                }
            }
        }
    }

    float* o = out + ((size_t)b * C * K + k) * SP + p;
#pragma unroll
    for (int c = 0; c < C; ++c)
        o[(size_t)c * K * SP] = acc[c >> 2][c & 3];
}

extern "C" void kernel_launch(void* const* d_in, const int* in_sizes, int n_in,
                              void* d_out, int out_size, void* d_ws, size_t ws_size,
                              hipStream_t stream) {
    const float* x = (const float*)d_in[0];
    const float* off = (const float*)d_in[1];
    float* out = (float*)d_out;

    const size_t xt_bytes = (size_t)B * SP * C * sizeof(float);
    const int n_main = B * K * SP;
    const int grid_main = (n_main + 255) / 256;

    if (ws_size >= xt_bytes) {
        float* xt = (float*)d_ws;
        const int n_x = B * SP;
        xpose_kernel<<<(n_x + 255) / 256, 256, 0, stream>>>(x, xt);
        deform_kernel<true><<<grid_main, 256, 0, stream>>>(xt, off, out);
    } else {
        deform_kernel<false><<<grid_main, 256, 0, stream>>>(x, off, out);
    }
}

// Round 2
// 158.600 us; speedup vs baseline: 1.2969x; 1.2969x over previous
//
#include <hip/hip_runtime.h>

typedef float f4 __attribute__((ext_vector_type(4)));

constexpr int B = 2, C = 16, D = 24, H = 48, W = 48;
constexpr int K = 27;
constexpr int SP = D * H * W;   // 55296 == P (stride 1, pad 1, dil 1, k=3)
constexpr int HW = H * W;

// x [B, C, S] -> xt [B, S, C]  (one spatial point's 16 channels = one 64B block)
__global__ __launch_bounds__(256) void xpose_kernel(const float* __restrict__ x,
                                                    float* __restrict__ xt) {
    int t = blockIdx.x * blockDim.x + threadIdx.x;
    if (t >= B * SP) return;
    int s = t % SP, b = t / SP;
    const float* src = x + (size_t)b * C * SP + s;
    f4 v[4];
#pragma unroll
    for (int q = 0; q < 4; ++q)
#pragma unroll
        for (int j = 0; j < 4; ++j)
            v[q][j] = src[(size_t)(q * 4 + j) * SP];
    f4* dst = reinterpret_cast<f4*>(xt + (size_t)t * 16);
#pragma unroll
    for (int q = 0; q < 4; ++q) dst[q] = v[q];
}

// 4 lanes per (b,k,p) sample: lane handles channel-quad q = tid&3.
// Cluster of 4 lanes reads one contiguous 64B block per trilinear corner.
__global__ __launch_bounds__(256) void deform_kernel_q(const float* __restrict__ xt,
                                                       const float* __restrict__ off,
                                                       float* __restrict__ out) {
    int tid = blockIdx.x * blockDim.x + threadIdx.x;
    int q = tid & 3;
    int s = tid >> 2;
    if (s >= B * K * SP) return;
    int p = s % SP;
    int bk = s / SP;
    int k = bk % K, b = bk / K;

    // offset channel layout: [B, K*3, P], channel = 3*k + {0,1,2}
    const float* ob = off + ((size_t)b * (3 * K) + 3 * k) * SP + p;
    float offd = __builtin_nontemporal_load(ob);
    float offh = __builtin_nontemporal_load(ob + (size_t)SP);
    float offw = __builtin_nontemporal_load(ob + (size_t)2 * SP);

    int od = p / HW, rem = p - od * HW;
    int oh = rem / W, ow = rem - oh * W;
    int ki = k / 9, kr = k - ki * 9;
    int kj = kr / 3, kk = kr - kj * 3;

    float pd = (float)(od + ki - 1) + offd;
    float ph = (float)(oh + kj - 1) + offh;
    float pw = (float)(ow + kk - 1) + offw;

    float d0f = floorf(pd), h0f = floorf(ph), w0f = floorf(pw);
    float fd = pd - d0f, fh = ph - h0f, fw = pw - w0f;
    int d0 = (int)d0f, h0 = (int)h0f, w0 = (int)w0f;

    const f4* xb = reinterpret_cast<const f4*>(xt) + (size_t)b * SP * 4 + q;

    f4 acc = {};
#pragma unroll
    for (int ci = 0; ci < 2; ++ci) {
        int ds = d0 + ci;
        bool vd = (ds >= 0) & (ds < D);
        float wd = ci ? fd : 1.0f - fd;
        int dc = min(max(ds, 0), D - 1);
#pragma unroll
        for (int cj = 0; cj < 2; ++cj) {
            int hs = h0 + cj;
            bool vh = (hs >= 0) & (hs < H);
            float wh = cj ? fh : 1.0f - fh;
            int hc = min(max(hs, 0), H - 1);
#pragma unroll
            for (int ck = 0; ck < 2; ++ck) {
                int ws = w0 + ck;
                bool vw = (ws >= 0) & (ws < W);
                float ww = ck ? fw : 1.0f - fw;
                int wc = min(max(ws, 0), W - 1);
                float wgt = (vd & vh & vw) ? wd * wh * ww : 0.0f;
                int idx = (dc * H + hc) * W + wc;
                acc += wgt * xb[(size_t)idx * 4];
            }
        }
    }

    // out layout [B, C, K, P]; this thread owns channels 4q..4q+3
    float* o = out + (((size_t)b * C + 4 * q) * K + k) * SP + p;
#pragma unroll
    for (int j = 0; j < 4; ++j)
        __builtin_nontemporal_store(acc[j], o + (size_t)j * K * SP);
}

// fallback (no workspace): one thread per sample, gather from native layout
__global__ __launch_bounds__(256) void deform_kernel_nat(const float* __restrict__ x,
                                                         const float* __restrict__ off,
                                                         float* __restrict__ out) {
    int tid = blockIdx.x * blockDim.x + threadIdx.x;
    if (tid >= B * K * SP) return;
    int p = tid % SP;
    int bk = tid / SP;
    int k = bk % K, b = bk / K;

    const float* ob = off + ((size_t)b * (3 * K) + 3 * k) * SP + p;
    float offd = ob[0];
    float offh = ob[(size_t)SP];
    float offw = ob[(size_t)2 * SP];

    int od = p / HW, rem = p - od * HW;
    int oh = rem / W, ow = rem - oh * W;
    int ki = k / 9, kr = k - ki * 9;
    int kj = kr / 3, kk = kr - kj * 3;

    float pd = (float)(od + ki - 1) + offd;
    float ph = (float)(oh + kj - 1) + offh;
    float pw = (float)(ow + kk - 1) + offw;

    float d0f = floorf(pd), h0f = floorf(ph), w0f = floorf(pw);
    float fd = pd - d0f, fh = ph - h0f, fw = pw - w0f;
    int d0 = (int)d0f, h0 = (int)h0f, w0 = (int)w0f;

    f4 acc[4] = {};
#pragma unroll
    for (int ci = 0; ci < 2; ++ci) {
        int ds = d0 + ci;
        bool vd = (ds >= 0) & (ds < D);
        float wd = ci ? fd : 1.0f - fd;
        int dc = min(max(ds, 0), D - 1);
#pragma unroll
        for (int cj = 0; cj < 2; ++cj) {
            int hs = h0 + cj;
            bool vh = (hs >= 0) & (hs < H);
            float wh = cj ? fh : 1.0f - fh;
            int hc = min(max(hs, 0), H - 1);
#pragma unroll
            for (int ck = 0; ck < 2; ++ck) {
                int ws = w0 + ck;
                bool vw = (ws >= 0) & (ws < W);
                float ww = ck ? fw : 1.0f - fw;
                int wc = min(max(ws, 0), W - 1);
                float wgt = (vd & vh & vw) ? wd * wh * ww : 0.0f;
                int idx = (dc * H + hc) * W + wc;
                const float* src = x + (size_t)b * C * SP + idx;
#pragma unroll
                for (int c = 0; c < C; ++c)
                    acc[c >> 2][c & 3] += wgt * src[(size_t)c * SP];
            }
        }
    }

    float* o = out + ((size_t)b * C * K + k) * SP + p;
#pragma unroll
    for (int c = 0; c < C; ++c)
        o[(size_t)c * K * SP] = acc[c >> 2][c & 3];
}

extern "C" void kernel_launch(void* const* d_in, const int* in_sizes, int n_in,
                              void* d_out, int out_size, void* d_ws, size_t ws_size,
                              hipStream_t stream) {
    const float* x = (const float*)d_in[0];
    const float* off = (const float*)d_in[1];
    float* out = (float*)d_out;

    const size_t xt_bytes = (size_t)B * SP * C * sizeof(float);

    if (ws_size >= xt_bytes) {
        float* xt = (float*)d_ws;
        const int n_x = B * SP;
        xpose_kernel<<<(n_x + 255) / 256, 256, 0, stream>>>(x, xt);
        const long long n4 = (long long)B * K * SP * 4;
        const int grid4 = (int)((n4 + 255) / 256);
        deform_kernel_q<<<grid4, 256, 0, stream>>>(xt, off, out);
    } else {
        const int n_main = B * K * SP;
        deform_kernel_nat<<<(n_main + 255) / 256, 256, 0, stream>>>(x, off, out);
    }
}

// Round 3
// 116.281 us; speedup vs baseline: 1.7689x; 1.3639x over previous
//
#include <hip/hip_runtime.h>
#include <hip/hip_bf16.h>

typedef float f4 __attribute__((ext_vector_type(4)));
typedef unsigned int u32;
typedef u32 u4 __attribute__((ext_vector_type(4)));

constexpr int B = 2, C = 16, D = 24, H = 48, W = 48;
constexpr int K = 27;
constexpr int SP = D * H * W;   // 55296
constexpr int HW = H * W;

__device__ inline ushort bf16_bits(float f) {
    __hip_bfloat16 h = __float2bfloat16(f);   // RTN-E
    return __builtin_bit_cast(ushort, h);
}

// x [B,C,S] f32 -> xt [B,S,16ch] bf16 (32 B per spatial point)
__global__ __launch_bounds__(256) void xpose_bf16_kernel(const float* __restrict__ x,
                                                         u32* __restrict__ xt) {
    int t = blockIdx.x * blockDim.x + threadIdx.x;
    if (t >= B * SP) return;
    int s = t % SP, b = t / SP;
    const float* src = x + (size_t)b * C * SP + s;
    u4 pk[2];
#pragma unroll
    for (int m = 0; m < 8; ++m) {
        float lo = src[(size_t)(2 * m) * SP];
        float hi = src[(size_t)(2 * m + 1) * SP];
        pk[m >> 2][m & 3] = (u32)bf16_bits(lo) | ((u32)bf16_bits(hi) << 16);
    }
    u4* dst = reinterpret_cast<u4*>(xt + (size_t)t * 8);
    dst[0] = pk[0];
    dst[1] = pk[1];
}

// 2 lanes per (b,k,p) sample: lane q=tid&1 owns channels 8q..8q+7.
// Per trilinear corner: one dwordx4 = 8 bf16 channels. LDS transpose -> dwordx4 stores.
__global__ __launch_bounds__(256, 8) void deform_bf16_kernel(const u32* __restrict__ xt,
                                                             const float* __restrict__ off,
                                                             float* __restrict__ out) {
    const int tid = blockIdx.x * blockDim.x + threadIdx.x;
    const int q = tid & 1;
    const int u = tid >> 1;                 // sample id, grid is exact
    const int p = u % SP;
    const int bk = u / SP;
    const int k = bk % K, b = bk / K;

    // offset layout [B, K*3, P], channels 3k..3k+2
    const float* ob = off + ((size_t)b * (3 * K) + 3 * k) * SP + p;
    float offd = __builtin_nontemporal_load(ob);
    float offh = __builtin_nontemporal_load(ob + (size_t)SP);
    float offw = __builtin_nontemporal_load(ob + (size_t)2 * SP);

    int od = p / HW, rem = p - od * HW;
    int oh = rem / W, ow = rem - oh * W;
    int ki = k / 9, kr = k - ki * 9;
    int kj = kr / 3, kk = kr - kj * 3;

    float pd = (float)(od + ki - 1) + offd;
    float ph = (float)(oh + kj - 1) + offh;
    float pw = (float)(ow + kk - 1) + offw;

    float d0f = floorf(pd), h0f = floorf(ph), w0f = floorf(pw);
    float fd = pd - d0f, fh = ph - h0f, fw = pw - w0f;
    int d0 = (int)d0f, h0 = (int)h0f, w0 = (int)w0f;

    // base: +q selects this lane's 16B half of the 32B point record
    const u4* xb = reinterpret_cast<const u4*>(xt) + (size_t)b * SP * 2 + q;

    float acc[8] = {};
#pragma unroll
    for (int ci = 0; ci < 2; ++ci) {
        int ds = d0 + ci;
        bool vd = (ds >= 0) & (ds < D);
        float wd = ci ? fd : 1.0f - fd;
        int dc = min(max(ds, 0), D - 1);
#pragma unroll
        for (int cj = 0; cj < 2; ++cj) {
            int hs = h0 + cj;
            bool vh = (hs >= 0) & (hs < H);
            float wh = cj ? fh : 1.0f - fh;
            int hc = min(max(hs, 0), H - 1);
#pragma unroll
            for (int ck = 0; ck < 2; ++ck) {
                int ws = w0 + ck;
                bool vw = (ws >= 0) & (ws < W);
                float ww = ck ? fw : 1.0f - fw;
                int wc = min(max(ws, 0), W - 1);
                float wgt = (vd & vh & vw) ? wd * wh * ww : 0.0f;
                int idx = (dc * H + hc) * W + wc;
                u4 v = xb[(size_t)idx * 2];
#pragma unroll
                for (int m = 0; m < 4; ++m) {
                    u32 wbits = v[m];
                    float lo = __builtin_bit_cast(float, wbits << 16);
                    float hi = __builtin_bit_cast(float, wbits & 0xffff0000u);
                    acc[2 * m] += wgt * lo;
                    acc[2 * m + 1] += wgt * hi;
                }
            }
        }
    }

    // wave-local transpose: [p-cluster][ch] -> [ch][p] so stores are full 128B lines
    __shared__ float lds[4][16][36];            // 36-pad: conflict-free both phases
    const int l = threadIdx.x & 63;
    const int wv = threadIdx.x >> 6;
    const int c = l >> 1;                       // p-local index 0..31
    float(*tile)[36] = lds[wv];
#pragma unroll
    for (int j = 0; j < 8; ++j) tile[8 * q + j][c] = acc[j];
    __syncthreads();

    const size_t p_base = (size_t)(p - c);      // wave's first p (32-aligned)
    float* obase = out + (((size_t)b * C) * K + k) * SP + p_base;
#pragma unroll
    for (int r = 0; r < 2; ++r) {
        int ch = 8 * r + (l >> 3);
        int p0 = 4 * (l & 7);
        f4 v = *reinterpret_cast<const f4*>(&tile[ch][p0]);
        *reinterpret_cast<f4*>(obase + (size_t)ch * K * SP + p0) = v;
    }
}

// fallback (no workspace): one thread per sample, gather from native fp32 layout
__global__ __launch_bounds__(256) void deform_kernel_nat(const float* __restrict__ x,
                                                         const float* __restrict__ off,
                                                         float* __restrict__ out) {
    int tid = blockIdx.x * blockDim.x + threadIdx.x;
    if (tid >= B * K * SP) return;
    int p = tid % SP;
    int bk = tid / SP;
    int k = bk % K, b = bk / K;

    const float* ob = off + ((size_t)b * (3 * K) + 3 * k) * SP + p;
    float offd = ob[0];
    float offh = ob[(size_t)SP];
    float offw = ob[(size_t)2 * SP];

    int od = p / HW, rem = p - od * HW;
    int oh = rem / W, ow = rem - oh * W;
    int ki = k / 9, kr = k - ki * 9;
    int kj = kr / 3, kk = kr - kj * 3;

    float pd = (float)(od + ki - 1) + offd;
    float ph = (float)(oh + kj - 1) + offh;
    float pw = (float)(ow + kk - 1) + offw;

    float d0f = floorf(pd), h0f = floorf(ph), w0f = floorf(pw);
    float fd = pd - d0f, fh = ph - h0f, fw = pw - w0f;
    int d0 = (int)d0f, h0 = (int)h0f, w0 = (int)w0f;

    f4 acc[4] = {};
#pragma unroll
    for (int ci = 0; ci < 2; ++ci) {
        int ds = d0 + ci;
        bool vd = (ds >= 0) & (ds < D);
        float wd = ci ? fd : 1.0f - fd;
        int dc = min(max(ds, 0), D - 1);
#pragma unroll
        for (int cj = 0; cj < 2; ++cj) {
            int hs = h0 + cj;
            bool vh = (hs >= 0) & (hs < H);
            float wh = cj ? fh : 1.0f - fh;
            int hc = min(max(hs, 0), H - 1);
#pragma unroll
            for (int ck = 0; ck < 2; ++ck) {
                int ws = w0 + ck;
                bool vw = (ws >= 0) & (ws < W);
                float ww = ck ? fw : 1.0f - fw;
                int wc = min(max(ws, 0), W - 1);
                float wgt = (vd & vh & vw) ? wd * wh * ww : 0.0f;
                int idx = (dc * H + hc) * W + wc;
                const float* src = x + (size_t)b * C * SP + idx;
#pragma unroll
                for (int c2 = 0; c2 < C; ++c2)
                    acc[c2 >> 2][c2 & 3] += wgt * src[(size_t)c2 * SP];
            }
        }
    }

    float* o = out + ((size_t)b * C * K + k) * SP + p;
#pragma unroll
    for (int c2 = 0; c2 < C; ++c2)
        o[(size_t)c2 * K * SP] = acc[c2 >> 2][c2 & 3];
}

extern "C" void kernel_launch(void* const* d_in, const int* in_sizes, int n_in,
                              void* d_out, int out_size, void* d_ws, size_t ws_size,
                              hipStream_t stream) {
    const float* x = (const float*)d_in[0];
    const float* off = (const float*)d_in[1];
    float* out = (float*)d_out;

    const size_t xt_bytes = (size_t)B * SP * 16 * sizeof(ushort);  // 3.5 MB

    if (ws_size >= xt_bytes) {
        u32* xt = (u32*)d_ws;
        const int n_x = B * SP;
        xpose_bf16_kernel<<<(n_x + 255) / 256, 256, 0, stream>>>(x, xt);
        const long long n2 = (long long)B * K * SP * 2;            // 5,971,968
        const int grid2 = (int)((n2 + 255) / 256);                 // exact: 23328
        deform_bf16_kernel<<<grid2, 256, 0, stream>>>(xt, off, out);
    } else {
        const int n_main = B * K * SP;
        deform_kernel_nat<<<(n_main + 255) / 256, 256, 0, stream>>>(x, off, out);
    }
}